// Round 2
// baseline (1477.665 us; speedup 1.0000x reference)
//
#include <hip/hip_runtime.h>
#include <hip/hip_bf16.h>
#include <stdint.h>

#define LN_EPS 1e-5f

typedef __bf16 bf16x8 __attribute__((ext_vector_type(8)));
typedef float f32x4 __attribute__((ext_vector_type(4)));

__device__ __forceinline__ unsigned short f2bf(float x) {
  unsigned u = __float_as_uint(x);
  return (unsigned short)((u + 0x7fffu + ((u >> 16) & 1u)) >> 16);
}

__device__ __forceinline__ void gll16(const void* g, void* l) {
  __builtin_amdgcn_global_load_lds((__attribute__((address_space(1))) void*)g,
                                   (__attribute__((address_space(3))) void*)l, 16, 0, 0);
}

// ---- kernel 1: construct la/lb [8][16][4096] (order-4 tensor product + LN) ----
__global__ __launch_bounds__(256) void k_construct(
    const float* __restrict__ wla, const float* __restrict__ wlb,
    const float* __restrict__ ln1w, const float* __restrict__ ln1b,
    const float* __restrict__ ln2w, const float* __restrict__ ln2b,
    float* __restrict__ la, float* __restrict__ lb) {
  const int s = blockIdx.x;
  const int t = threadIdx.x;
  __shared__ float w01[1024];
  __shared__ float w23[1024];
  __shared__ float red[8];
  for (int g = 0; g < 2; ++g) {
    const float* wl = g ? wlb : wla;
    for (int half = 0; half < 2; ++half) {
      const float* lnw  = half ? ln2w : ln1w;
      const float* lnbv = half ? ln2b : ln1b;
      const float* w0 = wl + (2*half + 0)*1024 + s*128;
      const float* w1 = wl + (2*half + 1)*1024 + s*128;
      float* buf = half ? w23 : w01;
      float v[4];
      float sum = 0.f, sumsq = 0.f;
      #pragma unroll
      for (int q = 0; q < 4; ++q) {
        int idx = t + 256*q;
        int r = idx >> 6, m = idx & 63;
        float val = w0[r*8 + (m >> 3)] * w1[r*8 + (m & 7)];
        v[q] = val; sum += val; sumsq += val*val;
      }
      #pragma unroll
      for (int off = 32; off; off >>= 1) {
        sum   += __shfl_down(sum, off);
        sumsq += __shfl_down(sumsq, off);
      }
      if ((t & 63) == 0) { red[t >> 6] = sum; red[4 + (t >> 6)] = sumsq; }
      __syncthreads();
      float fs  = red[0] + red[1] + red[2] + red[3];
      float fss = red[4] + red[5] + red[6] + red[7];
      float mu  = fs * (1.f/1024.f);
      float var = fss * (1.f/1024.f) - mu*mu;
      float rs  = rsqrtf(var + LN_EPS);
      __syncthreads();   // red reads done before next reuse
      #pragma unroll
      for (int q = 0; q < 4; ++q) {
        int idx = t + 256*q;
        buf[idx] = (v[q] - mu) * rs * lnw[idx] + lnbv[idx];
      }
      __syncthreads();
    }
    float* dst = (g ? lb : la) + s*65536;
    for (int q = 0; q < 256; ++q) {
      int f = t + 256*q;
      int rb = (f >> 12) << 6;
      dst[f] = w01[rb + ((f >> 6) & 63)] * w23[rb + (f & 63)];
    }
    __syncthreads();
  }
}

// ---- kernel 2: per-batch mixture. A[b][r][d] f32; Bmb[b][o][0..31] bf16 (r-major, zero-padded) ----
__global__ __launch_bounds__(256) void k_mix(
    const float* __restrict__ la, const float* __restrict__ lb,
    const float* __restrict__ module_logits, const int* __restrict__ task_ids,
    float* __restrict__ A, unsigned short* __restrict__ Bmb) {
  int gid = blockIdx.x*256 + threadIdx.x;   // 0..32767
  int b = gid >> 12, d = gid & 4095;
  int task = task_ids[b];
  float mwv[8]; float ssum = 0.f;
  #pragma unroll
  for (int s = 0; s < 8; ++s) {
    float p = 1.f / (1.f + expf(-module_logits[task*8 + s]));
    mwv[s] = p; ssum += p;
  }
  float inv = 1.f / (ssum + 1e-12f);
  unsigned pk[8];
  #pragma unroll
  for (int r = 0; r < 16; ++r) {
    float av = 0.f, bv = 0.f;
    #pragma unroll
    for (int s = 0; s < 8; ++s) {
      float w = mwv[s] * inv;
      av += w * la[(s*16 + r)*4096 + d];
      bv += w * lb[(s*16 + r)*4096 + d];
    }
    A[(b*16 + r)*4096 + d] = av;
    unsigned hv = f2bf(bv);
    if (r & 1) pk[r >> 1] |= hv << 16; else pk[r >> 1] = hv;
  }
  uint4* dst = (uint4*)(Bmb + (size_t)gid*32);
  uint4 a0; a0.x = pk[0]; a0.y = pk[1]; a0.z = pk[2]; a0.w = pk[3];
  uint4 a1; a1.x = pk[4]; a1.y = pk[5]; a1.z = pk[6]; a1.w = pk[7];
  uint4 z;  z.x = 0; z.y = 0; z.z = 0; z.w = 0;
  dst[0] = a0; dst[1] = a1; dst[2] = z; dst[3] = z;
}

// ---- kernel 3: cast W -> bf16 ----
__global__ __launch_bounds__(256) void k_castw(const float* __restrict__ w,
                                               unsigned short* __restrict__ wb) {
  int i = blockIdx.x*256 + threadIdx.x;   // one float4 each, grid covers exactly 16M elems
  float4 v = ((const float4*)w)[i];
  uint2 o;
  o.x = (unsigned)f2bf(v.x) | ((unsigned)f2bf(v.y) << 16);
  o.y = (unsigned)f2bf(v.z) | ((unsigned)f2bf(v.w) << 16);
  ((uint2*)wb)[i] = o;
}

// ---- kernel 4: per row: xb = bf16(x); hb[row][0..31] = bf16(h/16) zero-padded ----
__global__ __launch_bounds__(256) void k_rowh(
    const float* __restrict__ x, const float* __restrict__ A,
    unsigned short* __restrict__ xb, unsigned short* __restrict__ hb) {
  int row = blockIdx.x;            // 0..16383
  int b = row >> 11;
  int t = threadIdx.x;
  const float* xrow = x + (size_t)row*4096;
  const float* Ab = A + b*65536;
  float p[16];
  #pragma unroll
  for (int r = 0; r < 16; ++r) p[r] = 0.f;
  #pragma unroll
  for (int c = 0; c < 4; ++c) {
    int d0 = c*1024 + t*4;
    float4 xv = *(const float4*)(xrow + d0);
    ushort4 o;
    o.x = f2bf(xv.x); o.y = f2bf(xv.y); o.z = f2bf(xv.z); o.w = f2bf(xv.w);
    *(ushort4*)(xb + (size_t)row*4096 + d0) = o;
    #pragma unroll
    for (int r = 0; r < 16; ++r) {
      float4 av = *(const float4*)(Ab + r*4096 + d0);
      p[r] += xv.x*av.x + xv.y*av.y + xv.z*av.z + xv.w*av.w;
    }
  }
  #pragma unroll
  for (int r = 0; r < 16; ++r)
    #pragma unroll
    for (int off = 32; off; off >>= 1) p[r] += __shfl_down(p[r], off);
  __shared__ float red[4][16];
  int wid = t >> 6, lane = t & 63;
  if (lane == 0) {
    #pragma unroll
    for (int r = 0; r < 16; ++r) red[wid][r] = p[r];
  }
  __syncthreads();
  if (t < 16) {
    float h = red[0][t] + red[1][t] + red[2][t] + red[3][t];
    hb[(size_t)row*32 + t] = f2bf(h * (1.0f/16.0f));
  } else if (t < 32) {
    hb[(size_t)row*32 + t] = 0;
  }
}

// ---- kernel 5: C = Xb·Wbᵀ + bias + peeled adapter K-slice (hb·Bmbᵀ) ----
__global__ __launch_bounds__(256) void k_gemm(
    const unsigned short* __restrict__ xb, const unsigned short* __restrict__ wb,
    const unsigned short* __restrict__ hb, const unsigned short* __restrict__ Bmb,
    const float* __restrict__ bias, float* __restrict__ out) {
  __shared__ int4 smem_[1024];           // 16 KiB: A [0,8K), B [8K,16K)
  char* lds = (char*)smem_;
  const int tid = threadIdx.x;
  const int nt = blockIdx.x & 31, mt = blockIdx.x >> 5;
  const int row0 = mt << 7, col0 = nt << 7;
  const int b = row0 >> 11;              // 128-row tile never crosses batch boundary
  const int wid = tid >> 6, lane = tid & 63;
  const int wr = wid >> 1, wc = wid & 1;

  size_t srcA[2], srcB[2], srcAh[2], srcBh[2];
  #pragma unroll
  for (int k = 0; k < 2; ++k) {
    int r = k*64 + (tid >> 2);
    int cc = (tid & 3) ^ ((r >> 1) & 3);          // XOR swizzle (involution)
    srcA[k]  = (size_t)(row0 + r)*4096 + cc*8;
    srcB[k]  = (size_t)(col0 + r)*4096 + cc*8;
    srcAh[k] = (size_t)(row0 + r)*32 + cc*8;
    srcBh[k] = ((size_t)b*4096 + col0 + r)*32 + cc*8;
  }
  char* ldsA[2] = { lds + wid*1024,        lds + 4096  + wid*1024 };
  char* ldsB[2] = { lds + 8192 + wid*1024, lds + 12288 + wid*1024 };

  int aoff[4], boff[4];
  #pragma unroll
  for (int mf = 0; mf < 4; ++mf) {
    int r = wr*64 + mf*16 + (lane & 15);
    aoff[mf] = r*64 + (((lane >> 4) ^ ((r >> 1) & 3)) << 4);
  }
  #pragma unroll
  for (int nf = 0; nf < 4; ++nf) {
    int r = wc*64 + nf*16 + (lane & 15);
    boff[nf] = 8192 + r*64 + (((lane >> 4) ^ ((r >> 1) & 3)) << 4);
  }

  f32x4 zero = {0.f, 0.f, 0.f, 0.f};
  f32x4 acc[4][4];
  #pragma unroll
  for (int i = 0; i < 4; ++i)
    #pragma unroll
    for (int j = 0; j < 4; ++j) acc[i][j] = zero;

  for (int it = 0; it < 128; ++it) {
    const size_t ko = (size_t)it*32;
    gll16(xb + srcA[0] + ko, ldsA[0]);
    gll16(xb + srcA[1] + ko, ldsA[1]);
    gll16(wb + srcB[0] + ko, ldsB[0]);
    gll16(wb + srcB[1] + ko, ldsB[1]);
    __syncthreads();
    bf16x8 af[4], bfr[4];
    #pragma unroll
    for (int mf = 0; mf < 4; ++mf) af[mf] = *(const bf16x8*)(lds + aoff[mf]);
    #pragma unroll
    for (int nf = 0; nf < 4; ++nf) bfr[nf] = *(const bf16x8*)(lds + boff[nf]);
    #pragma unroll
    for (int mf = 0; mf < 4; ++mf)
      #pragma unroll
      for (int nf = 0; nf < 4; ++nf)
        acc[mf][nf] = __builtin_amdgcn_mfma_f32_16x16x32_bf16(af[mf], bfr[nf], acc[mf][nf], 0, 0, 0);
    __syncthreads();
  }
  // peeled adapter K-slice: A <- hb rows, B <- Bmb[b] rows (both zero-padded 16..31)
  gll16(hb + srcAh[0], ldsA[0]);
  gll16(hb + srcAh[1], ldsA[1]);
  gll16(Bmb + srcBh[0], ldsB[0]);
  gll16(Bmb + srcBh[1], ldsB[1]);
  __syncthreads();
  {
    bf16x8 af[4], bfr[4];
    #pragma unroll
    for (int mf = 0; mf < 4; ++mf) af[mf] = *(const bf16x8*)(lds + aoff[mf]);
    #pragma unroll
    for (int nf = 0; nf < 4; ++nf) bfr[nf] = *(const bf16x8*)(lds + boff[nf]);
    #pragma unroll
    for (int mf = 0; mf < 4; ++mf)
      #pragma unroll
      for (int nf = 0; nf < 4; ++nf)
        acc[mf][nf] = __builtin_amdgcn_mfma_f32_16x16x32_bf16(af[mf], bfr[nf], acc[mf][nf], 0, 0, 0);
  }
  // epilogue: + bias, store f32
  float bv[4];
  #pragma unroll
  for (int nf = 0; nf < 4; ++nf) bv[nf] = bias[col0 + wc*64 + nf*16 + (lane & 15)];
  #pragma unroll
  for (int mf = 0; mf < 4; ++mf) {
    int rowb = row0 + wr*64 + mf*16 + ((lane >> 4) << 2);
    #pragma unroll
    for (int nf = 0; nf < 4; ++nf) {
      int col = col0 + wc*64 + nf*16 + (lane & 15);
      #pragma unroll
      for (int q = 0; q < 4; ++q)
        out[(size_t)(rowb + q)*4096 + col] = acc[mf][nf][q] + bv[nf];
    }
  }
}

extern "C" void kernel_launch(void* const* d_in, const int* in_sizes, int n_in,
                              void* d_out, int out_size, void* d_ws, size_t ws_size,
                              hipStream_t stream) {
  const float* x             = (const float*)d_in[0];
  const int*   task_ids      = (const int*)d_in[1];
  const float* weight        = (const float*)d_in[2];
  const float* bias          = (const float*)d_in[3];
  const float* module_logits = (const float*)d_in[4];
  const float* wla           = (const float*)d_in[5];
  const float* wlb           = (const float*)d_in[6];
  const float* ln1w          = (const float*)d_in[7];
  const float* ln1b          = (const float*)d_in[8];
  const float* ln2w          = (const float*)d_in[9];
  const float* ln2b          = (const float*)d_in[10];
  float* out = (float*)d_out;

  char* ws = (char*)d_ws;
  unsigned short* xb = (unsigned short*)(ws);                        // 128 MiB
  unsigned short* wb = (unsigned short*)(ws + 134217728);            // 32 MiB
  float* la = (float*)(ws + 134217728 + 33554432);                   // 2 MiB
  float* lb = la + 524288;                                           // 2 MiB
  float* A  = lb + 524288;                                           // 2 MiB
  unsigned short* Bmb = (unsigned short*)(A + 524288);               // 2 MiB
  unsigned short* hb  = Bmb + 1048576;                               // 1 MiB

  k_construct<<<8, 256, 0, stream>>>(wla, wlb, ln1w, ln1b, ln2w, ln2b, la, lb);
  k_mix<<<128, 256, 0, stream>>>(la, lb, module_logits, task_ids, A, Bmb);
  k_castw<<<16384, 256, 0, stream>>>(weight, wb);
  k_rowh<<<16384, 256, 0, stream>>>(x, A, xb, hb);
  k_gemm<<<4096, 256, 0, stream>>>(xb, wb, hb, Bmb, bias, out);
}